// Round 1
// 275.275 us; speedup vs baseline: 1.0058x; 1.0058x over previous
//
#include <hip/hip_runtime.h>
#include <math.h>

#define EPS_C      1e-05f
#define PROJ_EPS_C 0.004f
#define MIN_NORM_C 1e-15f

#define NTOK   4096
#define DH     64
#define TILE   64
#define CHUNK2 128                 // phase2 tokens per block
#define NCHUNK2 (NTOK / CHUNK2)
#define PADROW 68
#define SUB    16                  // phase1: tokens per wave sub-tile

// component-wise FMA on named float4s: ACC += S * B
#define FMA4(ACC, S, B)                      \
    ACC.x = fmaf((S), (B).x, ACC.x);         \
    ACC.y = fmaf((S), (B).y, ACC.y);         \
    ACC.z = fmaf((S), (B).z, ACC.z);         \
    ACC.w = fmaf((S), (B).w, ACC.w);

#define ADD4(ACC, B)                         \
    ACC.x += (B).x; ACC.y += (B).y;          \
    ACC.z += (B).z; ACC.w += (B).w;

__device__ __forceinline__ float elup(float z) {
    // elu(z) + 1
    return z > 0.f ? z + 1.f : __expf(z);
}

// ---------------------------------------------------------------------------
// Phase 1 (rewritten): wave-private 16-token sub-tiles, 8x8 register tile per
// lane, no __syncthreads in the main loop. Cross-wave tree-reduce once per
// block, then coalesced partial stores (layouts unchanged vs old version).
// ---------------------------------------------------------------------------
__global__ __launch_bounds__(256, 4) void glin_phase1(
    const float* __restrict__ Kk, const float* __restrict__ Vv,
    const float* __restrict__ mask, const float* __restrict__ cc,
    int csize, int H, int chunk_toks, int BH,
    float* __restrict__ pt_out,
    float* __restrict__ part_v2, float* __restrict__ part_ctx)
{
    __shared__ __align__(16) float stg[4][2][SUB][PADROW];  // 34816 B, wave-private halves
    __shared__ __align__(16) float v2red[4][DH];            // 1 KB

    const int bh    = blockIdx.x;
    const int chunk = blockIdx.y;
    const int h     = bh % H;
    const float k   = cc[(csize == 1) ? 0 : h];

    const float* Kp = Kk + (size_t)bh * NTOK * DH;
    const float* Vp = Vv + (size_t)bh * NTOK * DH;
    float* ptp      = pt_out + (size_t)bh * NTOK;

    const int tid  = threadIdx.x;
    const int w    = tid >> 6;     // wave 0..3
    const int lane = tid & 63;
    const int r    = lane >> 3;    // 0..7  -> d-row block (8 rows of ctx)
    const int cg   = lane & 7;     // 0..7  -> e-col block (8 cols of ctx)
    const int srow = lane >> 4;    // staging: row-within-quad 0..3
    const int c4   = lane & 15;    // staging: float4 column 0..15

    float (*v2w)[PADROW] = stg[w][0];   // wave-private v2 tile [16][68]
    float (*xsw)[PADROW] = stg[w][1];   // wave-private xs tile [16][68]

    // 8x8 accumulator tile (rows r*8+i, cols cg*8 + j*4)
    float4 acc[8][2];
#pragma unroll
    for (int i = 0; i < 8; ++i) {
        acc[i][0] = make_float4(0.f, 0.f, 0.f, 0.f);
        acc[i][1] = make_float4(0.f, 0.f, 0.f, 0.f);
    }
    float4 va0 = make_float4(0.f, 0.f, 0.f, 0.f);   // v2 row-sums, rows r*8+0..3
    float4 va1 = make_float4(0.f, 0.f, 0.f, 0.f);   // rows r*8+4..7

    const int wtok  = chunk_toks >> 2;               // tokens owned by this wave
    const int wbase = chunk * chunk_toks + w * wtok;

    for (int s = 0; s < wtok; s += SUB) {
        // WAR fence: previous sub-tile's ds_reads must retire before overwrite
        asm volatile("s_waitcnt lgkmcnt(0)" ::: "memory");
        __builtin_amdgcn_sched_barrier(0);
        // ---- stage + transform 16 tokens (wave-private, no block barrier) ----
#pragma unroll
        for (int p = 0; p < 4; ++p) {
            const int row  = p * 4 + srow;           // 0..15
            const int gtok = wbase + s + row;
            float4 v4 = *(const float4*)(Vp + (size_t)gtok * DH + c4 * 4);
            float4 k4 = *(const float4*)(Kp + (size_t)gtok * DH + c4 * 4);
            float ss = v4.x * v4.x + v4.y * v4.y + v4.z * v4.z + v4.w * v4.w;
            ss += __shfl_xor(ss, 1);
            ss += __shfl_xor(ss, 2);
            ss += __shfl_xor(ss, 4);
            ss += __shfl_xor(ss, 8);
            float dpt   = fmaxf(1.f + k * ss, MIN_NORM_C);
            float pt    = 1.f / dpt;
            float gamma = 2.f * pt;
            float gm1   = gamma - 1.f;
            float sg    = (gm1 < 0.f) ? -1.f : 1.f;   // _sign(0) = +1
            float denomG = sg * fmaxf(fabsf(gm1), 1e-10f);
            float m     = mask[gtok];
            float xsc   = gamma / denomG * m;
            float a2    = denomG * m;
            if (c4 == 0) ptp[gtok] = pt;
            v4.x *= xsc; v4.y *= xsc; v4.z *= xsc; v4.w *= xsc;
            k4.x = a2 * elup(k4.x * pt);
            k4.y = a2 * elup(k4.y * pt);
            k4.z = a2 * elup(k4.z * pt);
            k4.w = a2 * elup(k4.w * pt);
            *(float4*)&xsw[row][c4 * 4] = v4;
            *(float4*)&v2w[row][c4 * 4] = k4;
        }
        // RAW fence: writes visible to cross-lane reads within the wave
        asm volatile("s_waitcnt lgkmcnt(0)" ::: "memory");
        __builtin_amdgcn_sched_barrier(0);
        // ---- 8x8 outer-product accumulate over 16 tokens ----
#pragma unroll 4
        for (int t = 0; t < SUB; ++t) {
            const float4 a0 = *(const float4*)&v2w[t][r * 8];
            const float4 a1 = *(const float4*)&v2w[t][r * 8 + 4];
            const float4 b0 = *(const float4*)&xsw[t][cg * 8];
            const float4 b1 = *(const float4*)&xsw[t][cg * 8 + 4];
            ADD4(va0, a0);
            ADD4(va1, a1);
            FMA4(acc[0][0], a0.x, b0); FMA4(acc[0][1], a0.x, b1);
            FMA4(acc[1][0], a0.y, b0); FMA4(acc[1][1], a0.y, b1);
            FMA4(acc[2][0], a0.z, b0); FMA4(acc[2][1], a0.z, b1);
            FMA4(acc[3][0], a0.w, b0); FMA4(acc[3][1], a0.w, b1);
            FMA4(acc[4][0], a1.x, b0); FMA4(acc[4][1], a1.x, b1);
            FMA4(acc[5][0], a1.y, b0); FMA4(acc[5][1], a1.y, b1);
            FMA4(acc[6][0], a1.z, b0); FMA4(acc[6][1], a1.z, b1);
            FMA4(acc[7][0], a1.w, b0); FMA4(acc[7][1], a1.w, b1);
        }
    }

    // ---- per-wave v2 row-sums to LDS (cg==0 lanes hold canonical copy) ----
    if (cg == 0) {
        *(float4*)&v2red[w][r * 8]     = va0;
        *(float4*)&v2red[w][r * 8 + 4] = va1;
    }
    __syncthreads();

    // ---- cross-wave ctx reduction, reusing staging LDS (8704 floats) ----
    float* red   = &stg[0][0][0][0];
    const int eo = cg * 8;
    if (w == 1) {
#pragma unroll
        for (int i = 0; i < 8; ++i) {
            *(float4*)&red[(r * 8 + i) * DH + eo]     = acc[i][0];
            *(float4*)&red[(r * 8 + i) * DH + eo + 4] = acc[i][1];
        }
    } else if (w == 3) {
#pragma unroll
        for (int i = 0; i < 8; ++i) {
            *(float4*)&red[4096 + (r * 8 + i) * DH + eo]     = acc[i][0];
            *(float4*)&red[4096 + (r * 8 + i) * DH + eo + 4] = acc[i][1];
        }
    }
    __syncthreads();
    if (w == 0) {
#pragma unroll
        for (int i = 0; i < 8; ++i) {
            float4 t0 = *(const float4*)&red[(r * 8 + i) * DH + eo];
            float4 t1 = *(const float4*)&red[(r * 8 + i) * DH + eo + 4];
            ADD4(acc[i][0], t0);
            ADD4(acc[i][1], t1);
        }
    } else if (w == 2) {
#pragma unroll
        for (int i = 0; i < 8; ++i) {
            float4 t0 = *(const float4*)&red[4096 + (r * 8 + i) * DH + eo];
            float4 t1 = *(const float4*)&red[4096 + (r * 8 + i) * DH + eo + 4];
            ADD4(acc[i][0], t0);
            ADD4(acc[i][1], t1);
        }
    } else if (w == 1) {
        // v2sum partial for this chunk (v2red complete since first barrier)
        float sv = v2red[0][lane] + v2red[1][lane] + v2red[2][lane] + v2red[3][lane];
        part_v2[((size_t)chunk * BH + bh) * DH + lane] = sv;
    }
    __syncthreads();
    if (w == 2) {
#pragma unroll
        for (int i = 0; i < 8; ++i) {
            *(float4*)&red[(r * 8 + i) * DH + eo]     = acc[i][0];
            *(float4*)&red[(r * 8 + i) * DH + eo + 4] = acc[i][1];
        }
    }
    __syncthreads();
    if (w == 0) {
        float* pc = part_ctx + ((size_t)chunk * BH + bh) * (DH * DH);
#pragma unroll
        for (int i = 0; i < 8; ++i) {
            float4 t0 = *(const float4*)&red[(r * 8 + i) * DH + eo];
            float4 t1 = *(const float4*)&red[(r * 8 + i) * DH + eo + 4];
            ADD4(acc[i][0], t0);
            ADD4(acc[i][1], t1);
            *(float4*)&pc[(r * 8 + i) * DH + eo]     = acc[i][0];
            *(float4*)&pc[(r * 8 + i) * DH + eo + 4] = acc[i][1];
        }
    }
}

// ---------------------------------------------------------------------------
// Reduce partials: ctx[bh][e] = sum_c part_ctx[c][bh][e]; same for v2sum.
// Widened: grid (BH, 16), 256 threads, 1 ctx element per thread (was 1 blk/CU).
// ---------------------------------------------------------------------------
__global__ __launch_bounds__(256) void glin_reduce(
    const float* __restrict__ part_ctx, const float* __restrict__ part_v2,
    int P, int BH,
    float* __restrict__ ctx_out, float* __restrict__ v2sum_out)
{
    const int bh   = blockIdx.x;
    const int q    = blockIdx.y;       // 0..15
    const int tid  = threadIdx.x;
    const int base = q * 256 + tid;

    float s0 = 0.f;
    for (int c = 0; c < P; ++c)
        s0 += part_ctx[((size_t)c * BH + bh) * (DH * DH) + base];
    ctx_out[(size_t)bh * DH * DH + base] = s0;

    if (q == 0 && tid < DH) {
        float s = 0.f;
        for (int c = 0; c < P; ++c)
            s += part_v2[((size_t)c * BH + bh) * DH + tid];
        v2sum_out[(size_t)bh * DH + tid] = s;
    }
}

// ---------------------------------------------------------------------------
// Phase 2 epilogue: Dinv scale, project -> mobius(0.5) -> project, store.
// ---------------------------------------------------------------------------
__device__ __forceinline__ void epilogue_store(
    float4 x, float dv, float k, float sk, float maxnorm,
    float* __restrict__ outp, int gtok, int tx)
{
    x.x *= dv; x.y *= dv; x.z *= dv; x.w *= dv;
    float n2 = x.x * x.x + x.y * x.y + x.z * x.z + x.w * x.w;
    n2 += __shfl_xor(n2, 1);
    n2 += __shfl_xor(n2, 2);
    n2 += __shfl_xor(n2, 4);
    n2 += __shfl_xor(n2, 8);
    float n  = fmaxf(sqrtf(n2), MIN_NORM_C);
    float scale = 1.f;
    float n1 = n;
    if (n > maxnorm) { scale = maxnorm / n; n1 = maxnorm; }
    float xn = fmaxf(n1, MIN_NORM_C);
    float s2;
    if (k < 0.f) {
        float t = fminf(sk * xn, 1.f - 1e-7f);
        s2 = 1.f / (1.f + sqrtf(fmaxf(1.f - t * t, 0.f)));
    } else {
        float t = sk * xn;
        s2 = 1.f / (1.f + sqrtf(1.f + t * t));
    }
    scale *= s2;
    float nrm2 = fmaxf(n1 * s2, MIN_NORM_C);
    if (nrm2 > maxnorm) scale *= maxnorm / nrm2;
    float4 o;
    o.x = x.x * scale; o.y = x.y * scale;
    o.z = x.z * scale; o.w = x.w * scale;
    *(float4*)(outp + (size_t)gtok * DH + tx * 4) = o;
}

// ---------------------------------------------------------------------------
// Phase 2: v1 = elup(Q*pt); D = v1.v2_sum; X = (v1 @ ctx)/D; epilogue.
// ---------------------------------------------------------------------------
__global__ __launch_bounds__(256, 4) void glin_phase2(
    const float* __restrict__ Qq, const float* __restrict__ cc,
    int csize, int H,
    const float* __restrict__ pt_in, const float* __restrict__ v2sum_in,
    const float* __restrict__ ctx_in, float* __restrict__ out)
{
    __shared__ __align__(16) float ctxs[DH][PADROW];
    __shared__ __align__(16) float v1s[TILE][PADROW];  // natural [token][dim]
    __shared__ __align__(16) float v2sum[DH];
    __shared__ float dinv[TILE];
    __shared__ __align__(16) float ptl[CHUNK2];

    const int bh    = blockIdx.x;
    const int chunk = blockIdx.y;
    const int h     = bh % H;
    const float k   = cc[(csize == 1) ? 0 : h];
    const float sk  = sqrtf(fabsf(k) + MIN_NORM_C);
    const float maxnorm = (k < 0.f) ? (1.f - PROJ_EPS_C) / sk : 1e15f;

    const int tid = threadIdx.x;
    const int ty  = tid >> 4;
    const int tx  = tid & 15;

    const float* Qp = Qq + (size_t)bh * NTOK * DH;
    float* outp     = out + (size_t)bh * NTOK * DH;

    // load context into LDS (padded)
#pragma unroll
    for (int p = 0; p < 4; ++p) {
        int f = tid + p * 256;
        int d = f >> 4, c4 = f & 15;
        float4 v = *(const float4*)(ctx_in + (size_t)bh * DH * DH + d * DH + c4 * 4);
        *(float4*)&ctxs[d][c4 * 4] = v;
    }
    if (tid < 16) {
        float4 v = *(const float4*)(v2sum_in + (size_t)bh * DH + tid * 4);
        *(float4*)&v2sum[tid * 4] = v;
    }
    if (tid < CHUNK2 / 4) {
        float4 v = *(const float4*)(pt_in + (size_t)bh * NTOK + chunk * CHUNK2 + tid * 4);
        *(float4*)&ptl[tid * 4] = v;
    }
    __syncthreads();

    const int tbase = chunk * CHUNK2;
    for (int tt = 0; tt < CHUNK2; tt += TILE) {
        // ---- build v1 tile (natural layout) + Dinv ----
#pragma unroll
        for (int p = 0; p < 4; ++p) {
            int f   = tid + p * 256;
            int row = f >> 4;        // local token 0..63
            int c4  = f & 15;
            int gtok = tbase + tt + row;
            float4 q4 = *(const float4*)(Qp + (size_t)gtok * DH + c4 * 4);
            float ptv = ptl[tt + row];
            float4 v1;
            v1.x = elup(q4.x * ptv);
            v1.y = elup(q4.y * ptv);
            v1.z = elup(q4.z * ptv);
            v1.w = elup(q4.w * ptv);
            float4 vs = *(const float4*)&v2sum[c4 * 4];
            float dp = v1.x * vs.x + v1.y * vs.y + v1.z * vs.z + v1.w * vs.w;
            dp += __shfl_xor(dp, 1);
            dp += __shfl_xor(dp, 2);
            dp += __shfl_xor(dp, 4);
            dp += __shfl_xor(dp, 8);
            if (c4 == 0) {
                float Dv = (dp == 0.f) ? EPS_C : dp;
                dinv[row] = 1.f / Dv;
            }
            *(float4*)&v1s[row][c4 * 4] = v1;
        }
        __syncthreads();
        // ---- X_tile = v1 @ context : 4 tokens (acc0..3) x 4 out-dims ----
        float4 acc0 = {0.f, 0.f, 0.f, 0.f};
        float4 acc1 = {0.f, 0.f, 0.f, 0.f};
        float4 acc2 = {0.f, 0.f, 0.f, 0.f};
        float4 acc3 = {0.f, 0.f, 0.f, 0.f};
#pragma unroll 8
        for (int db = 0; db < DH / 4; ++db) {
            float4 b0 = *(const float4*)&ctxs[db * 4 + 0][tx * 4];
            float4 b1 = *(const float4*)&ctxs[db * 4 + 1][tx * 4];
            float4 b2 = *(const float4*)&ctxs[db * 4 + 2][tx * 4];
            float4 b3 = *(const float4*)&ctxs[db * 4 + 3][tx * 4];
            float4 a0 = *(const float4*)&v1s[ty * 4 + 0][db * 4];
            FMA4(acc0, a0.x, b0); FMA4(acc0, a0.y, b1);
            FMA4(acc0, a0.z, b2); FMA4(acc0, a0.w, b3);
            float4 a1 = *(const float4*)&v1s[ty * 4 + 1][db * 4];
            FMA4(acc1, a1.x, b0); FMA4(acc1, a1.y, b1);
            FMA4(acc1, a1.z, b2); FMA4(acc1, a1.w, b3);
            float4 a2 = *(const float4*)&v1s[ty * 4 + 2][db * 4];
            FMA4(acc2, a2.x, b0); FMA4(acc2, a2.y, b1);
            FMA4(acc2, a2.z, b2); FMA4(acc2, a2.w, b3);
            float4 a3 = *(const float4*)&v1s[ty * 4 + 3][db * 4];
            FMA4(acc3, a3.x, b0); FMA4(acc3, a3.y, b1);
            FMA4(acc3, a3.z, b2); FMA4(acc3, a3.w, b3);
        }
        // ---- epilogue per token ----
        epilogue_store(acc0, dinv[ty * 4 + 0], k, sk, maxnorm, outp, tbase + tt + ty * 4 + 0, tx);
        epilogue_store(acc1, dinv[ty * 4 + 1], k, sk, maxnorm, outp, tbase + tt + ty * 4 + 1, tx);
        epilogue_store(acc2, dinv[ty * 4 + 2], k, sk, maxnorm, outp, tbase + tt + ty * 4 + 2, tx);
        epilogue_store(acc3, dinv[ty * 4 + 3], k, sk, maxnorm, outp, tbase + tt + ty * 4 + 3, tx);
        __syncthreads();   // protect v1s/dinv before next tile
    }
}

extern "C" void kernel_launch(void* const* d_in, const int* in_sizes, int n_in,
                              void* d_out, int out_size, void* d_ws, size_t ws_size,
                              hipStream_t stream)
{
    const float* Q    = (const float*)d_in[0];
    const float* K    = (const float*)d_in[1];
    const float* V    = (const float*)d_in[2];
    const float* mask = (const float*)d_in[3];
    const float* c    = (const float*)d_in[4];
    const int csize   = in_sizes[4];
    const int BH      = in_sizes[0] / (NTOK * DH);   // 64
    const int H       = 16;
    float* out        = (float*)d_out;

    // pick largest partial-chunk count P that fits the workspace
    int P = 16;
    while (P > 1) {
        size_t need = ((size_t)BH * NTOK                 // pt
                     + (size_t)BH * DH                   // v2sum
                     + (size_t)BH * DH * DH              // ctx
                     + (size_t)P * BH * DH               // part_v2
                     + (size_t)P * BH * DH * DH)         // part_ctx
                     * sizeof(float);
        if (need <= ws_size) break;
        P >>= 1;
    }
    const int chunk_toks = NTOK / P;

    // workspace layout
    float* pt       = (float*)d_ws;
    float* v2sum    = pt + (size_t)BH * NTOK;
    float* ctx      = v2sum + (size_t)BH * DH;
    float* part_v2  = ctx + (size_t)BH * DH * DH;
    float* part_ctx = part_v2 + (size_t)P * BH * DH;

    dim3 g1(BH, P);
    glin_phase1<<<g1, 256, 0, stream>>>(K, V, mask, c, csize, H, chunk_toks, BH,
                                        pt, part_v2, part_ctx);
    dim3 gr(BH, 16);
    glin_reduce<<<gr, 256, 0, stream>>>(part_ctx, part_v2, P, BH, ctx, v2sum);
    dim3 g2(BH, NCHUNK2);
    glin_phase2<<<g2, 256, 0, stream>>>(Q, c, csize, H, pt, v2sum, ctx, out);
}

// Round 3
// 268.208 us; speedup vs baseline: 1.0323x; 1.0263x over previous
//
#include <hip/hip_runtime.h>
#include <math.h>

#define EPS_C      1e-05f
#define PROJ_EPS_C 0.004f
#define MIN_NORM_C 1e-15f

#define NTOK   4096
#define DH     64
#define CHUNK2 256                 // phase2 tokens per block (64 per wave)
#define NCHUNK2 (NTOK / CHUNK2)    // 16 -> 1024 blocks = 4/CU exactly
#define PADROW 68
#define SUB    16                  // tokens per wave sub-tile (both phases)

// component-wise FMA on named float4s: ACC += S * B
#define FMA4(ACC, S, B)                      \
    ACC.x = fmaf((S), (B).x, ACC.x);         \
    ACC.y = fmaf((S), (B).y, ACC.y);         \
    ACC.z = fmaf((S), (B).z, ACC.z);         \
    ACC.w = fmaf((S), (B).w, ACC.w);

#define ADD4(ACC, B)                         \
    ACC.x += (B).x; ACC.y += (B).y;          \
    ACC.z += (B).z; ACC.w += (B).w;

// WAR/RAW pin: wait all LDS ops, and forbid compiler motion across this point
#define LDS_FENCE() do {                                   \
    asm volatile("s_waitcnt lgkmcnt(0)" ::: "memory");     \
    __builtin_amdgcn_sched_barrier(0);                     \
} while (0)

__device__ __forceinline__ float elup(float z) {
    // elu(z) + 1
    return z > 0.f ? z + 1.f : __expf(z);
}

// ---------------------------------------------------------------------------
// Phase 1: wave-private 16-token sub-tiles, 8x8 register tile per lane, no
// block barriers in main loop. K/V/mask register prefetch of the next
// sub-tile issued before the compute loop (HBM latency hides under FMAs).
// __launch_bounds__(256,3): VGPR cap ~170 for the prefetch regs (no spill).
// ---------------------------------------------------------------------------
__global__ __launch_bounds__(256, 3) void glin_phase1(
    const float* __restrict__ Kk, const float* __restrict__ Vv,
    const float* __restrict__ mask, const float* __restrict__ cc,
    int csize, int H, int chunk_toks, int BH,
    float* __restrict__ pt_out,
    float* __restrict__ part_v2, float* __restrict__ part_ctx)
{
    __shared__ __align__(16) float stg[4][2][SUB][PADROW];  // wave-private halves
    __shared__ __align__(16) float v2red[4][DH];

    const int bh    = blockIdx.x;
    const int chunk = blockIdx.y;
    const int h     = bh % H;
    const float k   = cc[(csize == 1) ? 0 : h];

    const float* Kp = Kk + (size_t)bh * NTOK * DH;
    const float* Vp = Vv + (size_t)bh * NTOK * DH;
    float* ptp      = pt_out + (size_t)bh * NTOK;

    const int tid  = threadIdx.x;
    const int w    = tid >> 6;     // wave 0..3
    const int lane = tid & 63;
    const int r    = lane >> 3;    // 0..7  -> d-row block
    const int cg   = lane & 7;     // 0..7  -> e-col block
    const int srow = lane >> 4;    // staging row-within-quad 0..3
    const int c4   = lane & 15;    // staging float4 column 0..15

    float (*v2w)[PADROW] = stg[w][0];
    float (*xsw)[PADROW] = stg[w][1];

    float4 acc[8][2];
#pragma unroll
    for (int i = 0; i < 8; ++i) {
        acc[i][0] = make_float4(0.f, 0.f, 0.f, 0.f);
        acc[i][1] = make_float4(0.f, 0.f, 0.f, 0.f);
    }
    float4 va0 = make_float4(0.f, 0.f, 0.f, 0.f);
    float4 va1 = make_float4(0.f, 0.f, 0.f, 0.f);

    const int wtok  = chunk_toks >> 2;
    const int wbase = chunk * chunk_toks + w * wtok;

    // single-buffer prefetch registers (reissued after consumption each iter)
    float4 pv0, pv1, pv2, pv3, pk0, pk1, pk2, pk3;
    float  pm0, pm1, pm2, pm3;

#define P1_LOAD(S) { \
    const float* vp_ = Vp + (size_t)(wbase + (S) + srow) * DH + c4 * 4; \
    const float* kp_ = Kp + (size_t)(wbase + (S) + srow) * DH + c4 * 4; \
    pv0 = *(const float4*)(vp_);            pk0 = *(const float4*)(kp_); \
    pv1 = *(const float4*)(vp_ + 4 * DH);   pk1 = *(const float4*)(kp_ + 4 * DH); \
    pv2 = *(const float4*)(vp_ + 8 * DH);   pk2 = *(const float4*)(kp_ + 8 * DH); \
    pv3 = *(const float4*)(vp_ + 12 * DH);  pk3 = *(const float4*)(kp_ + 12 * DH); \
    const float* mp_ = mask + wbase + (S) + srow; \
    pm0 = mp_[0]; pm1 = mp_[4]; pm2 = mp_[8]; pm3 = mp_[12]; \
}

#define P1_XF(PV, PK, PM, P, S) { \
    const int row_ = (P) * 4 + srow; \
    float ss = PV.x*PV.x + PV.y*PV.y + PV.z*PV.z + PV.w*PV.w; \
    ss += __shfl_xor(ss, 1); ss += __shfl_xor(ss, 2); \
    ss += __shfl_xor(ss, 4); ss += __shfl_xor(ss, 8); \
    const float dpt   = fmaxf(1.f + k * ss, MIN_NORM_C); \
    const float pt_   = 1.f / dpt; \
    const float gamma = 2.f * pt_; \
    const float gm1   = gamma - 1.f; \
    const float sg    = (gm1 < 0.f) ? -1.f : 1.f;   /* _sign(0)=+1 */ \
    const float denomG = sg * fmaxf(fabsf(gm1), 1e-10f); \
    const float xsc   = gamma / denomG * PM; \
    const float a2    = denomG * PM; \
    if (c4 == 0) ptp[wbase + (S) + row_] = pt_; \
    float4 xv; xv.x = PV.x*xsc; xv.y = PV.y*xsc; xv.z = PV.z*xsc; xv.w = PV.w*xsc; \
    float4 wv; wv.x = a2*elup(PK.x*pt_); wv.y = a2*elup(PK.y*pt_); \
               wv.z = a2*elup(PK.z*pt_); wv.w = a2*elup(PK.w*pt_); \
    *(float4*)&xsw[row_][c4 * 4] = xv; \
    *(float4*)&v2w[row_][c4 * 4] = wv; \
}

    P1_LOAD(0);
    for (int s = 0; s < wtok; s += SUB) {
        // WAR pin: previous sub-tile's ds_reads are consumed (lgkmcnt ~0 by
        // now) -- this exists to stop the COMPILER hoisting the staging
        // writes below above the prior tile's reads (cross-lane dep is
        // invisible to its per-thread alias model).
        LDS_FENCE();
        // transform prefetched regs -> LDS writes (consumes pv/pk/pm)
        P1_XF(pv0, pk0, pm0, 0, s);
        P1_XF(pv1, pk1, pm1, 1, s);
        P1_XF(pv2, pk2, pm2, 2, s);
        P1_XF(pv3, pk3, pm3, 3, s);
        // issue next sub-tile's global loads NOW -> complete during compute
        if (s + SUB < wtok) P1_LOAD(s + SUB);
        // RAW fence: staging writes visible to cross-lane reads in this wave
        LDS_FENCE();
        // ---- 8x8 outer-product accumulate over 16 tokens ----
#pragma unroll 4
        for (int t = 0; t < SUB; ++t) {
            const float4 a0 = *(const float4*)&v2w[t][r * 8];
            const float4 a1 = *(const float4*)&v2w[t][r * 8 + 4];
            const float4 b0 = *(const float4*)&xsw[t][cg * 8];
            const float4 b1 = *(const float4*)&xsw[t][cg * 8 + 4];
            ADD4(va0, a0);
            ADD4(va1, a1);
            FMA4(acc[0][0], a0.x, b0); FMA4(acc[0][1], a0.x, b1);
            FMA4(acc[1][0], a0.y, b0); FMA4(acc[1][1], a0.y, b1);
            FMA4(acc[2][0], a0.z, b0); FMA4(acc[2][1], a0.z, b1);
            FMA4(acc[3][0], a0.w, b0); FMA4(acc[3][1], a0.w, b1);
            FMA4(acc[4][0], a1.x, b0); FMA4(acc[4][1], a1.x, b1);
            FMA4(acc[5][0], a1.y, b0); FMA4(acc[5][1], a1.y, b1);
            FMA4(acc[6][0], a1.z, b0); FMA4(acc[6][1], a1.z, b1);
            FMA4(acc[7][0], a1.w, b0); FMA4(acc[7][1], a1.w, b1);
        }
    }

    // ---- per-wave v2 row-sums to LDS ----
    if (cg == 0) {
        *(float4*)&v2red[w][r * 8]     = va0;
        *(float4*)&v2red[w][r * 8 + 4] = va1;
    }
    __syncthreads();

    // ---- cross-wave ctx reduction, reusing staging LDS ----
    float* red   = &stg[0][0][0][0];
    const int eo = cg * 8;
    if (w == 1) {
#pragma unroll
        for (int i = 0; i < 8; ++i) {
            *(float4*)&red[(r * 8 + i) * DH + eo]     = acc[i][0];
            *(float4*)&red[(r * 8 + i) * DH + eo + 4] = acc[i][1];
        }
    } else if (w == 3) {
#pragma unroll
        for (int i = 0; i < 8; ++i) {
            *(float4*)&red[4096 + (r * 8 + i) * DH + eo]     = acc[i][0];
            *(float4*)&red[4096 + (r * 8 + i) * DH + eo + 4] = acc[i][1];
        }
    }
    __syncthreads();
    if (w == 0) {
#pragma unroll
        for (int i = 0; i < 8; ++i) {
            float4 t0 = *(const float4*)&red[(r * 8 + i) * DH + eo];
            float4 t1 = *(const float4*)&red[(r * 8 + i) * DH + eo + 4];
            ADD4(acc[i][0], t0);
            ADD4(acc[i][1], t1);
        }
    } else if (w == 2) {
#pragma unroll
        for (int i = 0; i < 8; ++i) {
            float4 t0 = *(const float4*)&red[4096 + (r * 8 + i) * DH + eo];
            float4 t1 = *(const float4*)&red[4096 + (r * 8 + i) * DH + eo + 4];
            ADD4(acc[i][0], t0);
            ADD4(acc[i][1], t1);
        }
    } else if (w == 1) {
        float sv = v2red[0][lane] + v2red[1][lane] + v2red[2][lane] + v2red[3][lane];
        part_v2[((size_t)chunk * BH + bh) * DH + lane] = sv;
    }
    __syncthreads();
    if (w == 2) {
#pragma unroll
        for (int i = 0; i < 8; ++i) {
            *(float4*)&red[(r * 8 + i) * DH + eo]     = acc[i][0];
            *(float4*)&red[(r * 8 + i) * DH + eo + 4] = acc[i][1];
        }
    }
    __syncthreads();
    if (w == 0) {
        float* pc = part_ctx + ((size_t)chunk * BH + bh) * (DH * DH);
#pragma unroll
        for (int i = 0; i < 8; ++i) {
            float4 t0 = *(const float4*)&red[(r * 8 + i) * DH + eo];
            float4 t1 = *(const float4*)&red[(r * 8 + i) * DH + eo + 4];
            ADD4(acc[i][0], t0);
            ADD4(acc[i][1], t1);
            *(float4*)&pc[(r * 8 + i) * DH + eo]     = acc[i][0];
            *(float4*)&pc[(r * 8 + i) * DH + eo + 4] = acc[i][1];
        }
    }
}

// ---------------------------------------------------------------------------
// Reduce partials (unchanged): ctx[bh][e] = sum_c part_ctx[c][bh][e].
// ---------------------------------------------------------------------------
__global__ __launch_bounds__(256) void glin_reduce(
    const float* __restrict__ part_ctx, const float* __restrict__ part_v2,
    int P, int BH,
    float* __restrict__ ctx_out, float* __restrict__ v2sum_out)
{
    const int bh   = blockIdx.x;
    const int q    = blockIdx.y;       // 0..15
    const int tid  = threadIdx.x;
    const int base = q * 256 + tid;

    float s0 = 0.f;
    for (int c = 0; c < P; ++c)
        s0 += part_ctx[((size_t)c * BH + bh) * (DH * DH) + base];
    ctx_out[(size_t)bh * DH * DH + base] = s0;

    if (q == 0 && tid < DH) {
        float s = 0.f;
        for (int c = 0; c < P; ++c)
            s += part_v2[((size_t)c * BH + bh) * DH + tid];
        v2sum_out[(size_t)bh * DH + tid] = s;
    }
}

// ---------------------------------------------------------------------------
// Phase 2 epilogue: Dinv scale, project -> mobius(0.5) -> project, store.
// ---------------------------------------------------------------------------
__device__ __forceinline__ void epilogue_store(
    float4 x, float dv, float k, float sk, float maxnorm,
    float* __restrict__ outp, int gtok, int tx)
{
    x.x *= dv; x.y *= dv; x.z *= dv; x.w *= dv;
    float n2 = x.x * x.x + x.y * x.y + x.z * x.z + x.w * x.w;
    n2 += __shfl_xor(n2, 1);
    n2 += __shfl_xor(n2, 2);
    n2 += __shfl_xor(n2, 4);
    n2 += __shfl_xor(n2, 8);
    float n  = fmaxf(sqrtf(n2), MIN_NORM_C);
    float scale = 1.f;
    float n1 = n;
    if (n > maxnorm) { scale = maxnorm / n; n1 = maxnorm; }
    float xn = fmaxf(n1, MIN_NORM_C);
    float s2;
    if (k < 0.f) {
        float t = fminf(sk * xn, 1.f - 1e-7f);
        s2 = 1.f / (1.f + sqrtf(fmaxf(1.f - t * t, 0.f)));
    } else {
        float t = sk * xn;
        s2 = 1.f / (1.f + sqrtf(1.f + t * t));
    }
    scale *= s2;
    float nrm2 = fmaxf(n1 * s2, MIN_NORM_C);
    if (nrm2 > maxnorm) scale *= maxnorm / nrm2;
    float4 o;
    o.x = x.x * scale; o.y = x.y * scale;
    o.z = x.z * scale; o.w = x.w * scale;
    *(float4*)(outp + (size_t)gtok * DH + tx * 4) = o;
}

// ---------------------------------------------------------------------------
// Phase 2: wave-private 16-token sub-tiles, zero block barriers in the main
// body (one barrier after the cooperative ctx/pt load), Q register prefetch
// ping-pong (qa/qb). 64 tokens per wave, CHUNK2=256.
// ---------------------------------------------------------------------------
__global__ __launch_bounds__(256, 4) void glin_phase2(
    const float* __restrict__ Qq, const float* __restrict__ cc,
    int csize, int H,
    const float* __restrict__ pt_in, const float* __restrict__ v2sum_in,
    const float* __restrict__ ctx_in, float* __restrict__ out)
{
    __shared__ __align__(16) float ctxs[DH][PADROW];       // 17408 B
    __shared__ __align__(16) float v1b[4][SUB][PADROW];    // 17408 B wave-private
    __shared__ __align__(16) float v2sum[DH];
    __shared__ __align__(16) float dinvw[4][SUB];
    __shared__ __align__(16) float ptl[CHUNK2];

    const int bh    = blockIdx.x;
    const int chunk = blockIdx.y;
    const int h     = bh % H;
    const float k   = cc[(csize == 1) ? 0 : h];
    const float sk  = sqrtf(fabsf(k) + MIN_NORM_C);
    const float maxnorm = (k < 0.f) ? (1.f - PROJ_EPS_C) / sk : 1e15f;

    const int tid  = threadIdx.x;
    const int w    = tid >> 6;     // wave 0..3
    const int lane = tid & 63;
    const int ty   = lane >> 4;    // 0..3 (token group / staging srow)
    const int tx   = lane & 15;    // 0..15 (col group / staging c4)

    const float* Qp = Qq + (size_t)bh * NTOK * DH;
    float* outp     = out + (size_t)bh * NTOK * DH;

    // cooperative loads (one barrier total)
#pragma unroll
    for (int p = 0; p < 4; ++p) {
        int f = tid + p * 256;
        int d = f >> 4, e4 = f & 15;
        *(float4*)&ctxs[d][e4 * 4] =
            *(const float4*)(ctx_in + (size_t)bh * DH * DH + d * DH + e4 * 4);
    }
    if (tid < 16)
        *(float4*)&v2sum[tid * 4] =
            *(const float4*)(v2sum_in + (size_t)bh * DH + tid * 4);
    if (tid < CHUNK2 / 4)
        *(float4*)&ptl[tid * 4] =
            *(const float4*)(pt_in + (size_t)bh * NTOK + chunk * CHUNK2 + tid * 4);
    __syncthreads();

    const int wloc = w * (CHUNK2 / 4);         // local token base of this wave
    const int wtb  = chunk * CHUNK2 + wloc;    // global token base of this wave

    float4 qa0, qa1, qa2, qa3, qb0, qb1, qb2, qb3;

#define P2_LOADQ(R0, R1, R2, R3, S) { \
    const float* qp_ = Qp + (size_t)(wtb + (S) + ty) * DH + tx * 4; \
    R0 = *(const float4*)(qp_); \
    R1 = *(const float4*)(qp_ + 4 * DH); \
    R2 = *(const float4*)(qp_ + 8 * DH); \
    R3 = *(const float4*)(qp_ + 12 * DH); \
}

#define P2_BUILD(R, P, S) { \
    const int row_ = (P) * 4 + ty; \
    const float ptv = ptl[wloc + (S) + row_]; \
    float4 v1; \
    v1.x = elup(R.x * ptv); v1.y = elup(R.y * ptv); \
    v1.z = elup(R.z * ptv); v1.w = elup(R.w * ptv); \
    const float4 vs = *(const float4*)&v2sum[tx * 4]; \
    float dp = v1.x*vs.x + v1.y*vs.y + v1.z*vs.z + v1.w*vs.w; \
    dp += __shfl_xor(dp, 1); dp += __shfl_xor(dp, 2); \
    dp += __shfl_xor(dp, 4); dp += __shfl_xor(dp, 8); \
    if (tx == 0) dinvw[w][row_] = 1.f / ((dp == 0.f) ? EPS_C : dp); \
    *(float4*)&v1b[w][row_][tx * 4] = v1; \
}

#define P2_TILE(R0, R1, R2, R3, S) { \
    /* WAR pin: prior tile's v1b/dinvw reads must not be crossed by the */ \
    /* staging writes below (compiler ordering only; lgkmcnt ~0 here).  */ \
    LDS_FENCE(); \
    P2_BUILD(R0, 0, S) P2_BUILD(R1, 1, S) P2_BUILD(R2, 2, S) P2_BUILD(R3, 3, S) \
    LDS_FENCE(); \
    float4 acc0 = make_float4(0.f, 0.f, 0.f, 0.f); \
    float4 acc1 = make_float4(0.f, 0.f, 0.f, 0.f); \
    float4 acc2 = make_float4(0.f, 0.f, 0.f, 0.f); \
    float4 acc3 = make_float4(0.f, 0.f, 0.f, 0.f); \
    _Pragma("unroll 8") \
    for (int db = 0; db < DH / 4; ++db) { \
        const float4 b0 = *(const float4*)&ctxs[db * 4 + 0][tx * 4]; \
        const float4 b1 = *(const float4*)&ctxs[db * 4 + 1][tx * 4]; \
        const float4 b2 = *(const float4*)&ctxs[db * 4 + 2][tx * 4]; \
        const float4 b3 = *(const float4*)&ctxs[db * 4 + 3][tx * 4]; \
        const float4 a0 = *(const float4*)&v1b[w][ty * 4 + 0][db * 4]; \
        FMA4(acc0, a0.x, b0); FMA4(acc0, a0.y, b1); FMA4(acc0, a0.z, b2); FMA4(acc0, a0.w, b3); \
        const float4 a1 = *(const float4*)&v1b[w][ty * 4 + 1][db * 4]; \
        FMA4(acc1, a1.x, b0); FMA4(acc1, a1.y, b1); FMA4(acc1, a1.z, b2); FMA4(acc1, a1.w, b3); \
        const float4 a2 = *(const float4*)&v1b[w][ty * 4 + 2][db * 4]; \
        FMA4(acc2, a2.x, b0); FMA4(acc2, a2.y, b1); FMA4(acc2, a2.z, b2); FMA4(acc2, a2.w, b3); \
        const float4 a3 = *(const float4*)&v1b[w][ty * 4 + 3][db * 4]; \
        FMA4(acc3, a3.x, b0); FMA4(acc3, a3.y, b1); FMA4(acc3, a3.z, b2); FMA4(acc3, a3.w, b3); \
    } \
    epilogue_store(acc0, dinvw[w][ty * 4 + 0], k, sk, maxnorm, outp, wtb + (S) + ty * 4 + 0, tx); \
    epilogue_store(acc1, dinvw[w][ty * 4 + 1], k, sk, maxnorm, outp, wtb + (S) + ty * 4 + 1, tx); \
    epilogue_store(acc2, dinvw[w][ty * 4 + 2], k, sk, maxnorm, outp, wtb + (S) + ty * 4 + 2, tx); \
    epilogue_store(acc3, dinvw[w][ty * 4 + 3], k, sk, maxnorm, outp, wtb + (S) + ty * 4 + 3, tx); \
}

    // 4 sub-tiles of 16 tokens, fully unrolled ping-pong prefetch
    P2_LOADQ(qa0, qa1, qa2, qa3, 0);
    P2_LOADQ(qb0, qb1, qb2, qb3, SUB);
    P2_TILE (qa0, qa1, qa2, qa3, 0);
    P2_LOADQ(qa0, qa1, qa2, qa3, 2 * SUB);
    P2_TILE (qb0, qb1, qb2, qb3, SUB);
    P2_LOADQ(qb0, qb1, qb2, qb3, 3 * SUB);
    P2_TILE (qa0, qa1, qa2, qa3, 2 * SUB);
    P2_TILE (qb0, qb1, qb2, qb3, 3 * SUB);
}

extern "C" void kernel_launch(void* const* d_in, const int* in_sizes, int n_in,
                              void* d_out, int out_size, void* d_ws, size_t ws_size,
                              hipStream_t stream)
{
    const float* Q    = (const float*)d_in[0];
    const float* K    = (const float*)d_in[1];
    const float* V    = (const float*)d_in[2];
    const float* mask = (const float*)d_in[3];
    const float* c    = (const float*)d_in[4];
    const int csize   = in_sizes[4];
    const int BH      = in_sizes[0] / (NTOK * DH);   // 64
    const int H       = 16;
    float* out        = (float*)d_out;

    // pick largest partial-chunk count P that fits the workspace
    int P = 16;
    while (P > 1) {
        size_t need = ((size_t)BH * NTOK                 // pt
                     + (size_t)BH * DH                   // v2sum
                     + (size_t)BH * DH * DH              // ctx
                     + (size_t)P * BH * DH               // part_v2
                     + (size_t)P * BH * DH * DH)         // part_ctx
                     * sizeof(float);
        if (need <= ws_size) break;
        P >>= 1;
    }
    const int chunk_toks = NTOK / P;

    // workspace layout
    float* pt       = (float*)d_ws;
    float* v2sum    = pt + (size_t)BH * NTOK;
    float* ctx      = v2sum + (size_t)BH * DH;
    float* part_v2  = ctx + (size_t)BH * DH * DH;
    float* part_ctx = part_v2 + (size_t)P * BH * DH;

    dim3 g1(BH, P);
    glin_phase1<<<g1, 256, 0, stream>>>(K, V, mask, c, csize, H, chunk_toks, BH,
                                        pt, part_v2, part_ctx);
    dim3 gr(BH, 16);
    glin_reduce<<<gr, 16 * sizeof(float) * 0 + 256, 0, stream>>>(part_ctx, part_v2, P, BH, ctx, v2sum);
    dim3 g2(BH, NCHUNK2);
    glin_phase2<<<g2, 256, 0, stream>>>(Q, c, csize, H, pt, v2sum, ctx, out);
}